// Round 5
// baseline (518.303 us; speedup 1.0000x reference)
//
#include <hip/hip_runtime.h>

// CRF loss, T=16384, L=1024. v13: depth 16 + fused aux kernels.
// v12 (286us) = 31 exchanges x 9.2us where the step cost is a latency PILE
// (compute 1 + drain 0.8 + flag 1 + pull 1.5 + stage/barriers 0.8 + skew),
// not one dominant term. Fix: halve the step count again. Perron contraction
// (~0.04/step) makes 16-step chunk products rank-1 to 1e-22, so BQ=16,
// KCH=64 chunks/group (4 MFMA B-tiles), NCH=1024 chunks/dir, 16 groups/dir
// x 8 parties = 256 blocks (1/CU, all co-resident). qs = 64 chunks x 1024
// f16 = 128KB LDS (gfx950 has 160KB/CU; v12's 66048B static already ran).
// Transport identical to proven v12: relaxed sc1 payload stores ->
// __syncthreads (vmcnt0 drain) -> per-party flag -> spin 8 flags -> pull
// untagged payload once (64 u64/thread, 2 batches) -> swizzled LDS stage.
// Aux fused: gold folded into crf_chunks (64 t/block, post-loop);
// transpose_k dropped (bwd A-init reads trans cols; 16 lanes x 4B are
// line-contiguous -> same transaction count); stitch+final merged via
// completion counter. 7 dispatches -> 4.

#define TT    16384
#define LLAB  1024
#define NEGV  -10000.0
#define BQ    16            // steps per chunk
#define NCH   1024          // chunks per direction (TT/BQ)
#define KCH   64            // chunks per group (4 MFMA N-tiles)
#define NPTY  8             // parties per group
#define AGT   __HIP_MEMORY_SCOPE_AGENT

typedef unsigned long long u64;
typedef unsigned int u32;
typedef unsigned short u16;
typedef _Float16 f16;
typedef _Float16 h2 __attribute__((ext_vector_type(2)));
typedef _Float16 f16x8 __attribute__((ext_vector_type(8)));
typedef float f32x4 __attribute__((ext_vector_type(4)));

__device__ __forceinline__ void pub64(u64* p, u64 v) {
  __hip_atomic_store(p, v, __ATOMIC_RELAXED, AGT);
}
__device__ __forceinline__ u64 ald64(const u64* p) {
  return __hip_atomic_load(p, __ATOMIC_RELAXED, AGT);
}
__device__ __forceinline__ u32 pack2(float a, float b) {
  h2 h = {(f16)a, (f16)b};
  return __builtin_bit_cast(u32, h);
}
__device__ __forceinline__ float f16lo(u32 b) {
  return (float)__builtin_bit_cast(f16, (u16)(b & 0xFFFFu));
}
__device__ __forceinline__ float f16hi(u32 b) {
  return (float)__builtin_bit_cast(f16, (u16)(b >> 16));
}
// XOR swizzle on u32-word index within a chunk's 512-word block (bits 2..4).
__device__ __forceinline__ int swz(int c, int w) { return w ^ ((c & 7) << 2); }

__device__ __forceinline__ float max8(uint4 v) {
  float m = fmaxf(fmaxf(f16lo(v.x), f16hi(v.x)), fmaxf(f16lo(v.y), f16hi(v.y)));
  m = fmaxf(m, fmaxf(f16lo(v.z), f16hi(v.z)));
  m = fmaxf(m, fmaxf(f16lo(v.w), f16hi(v.w)));
  return m;
}

// ---------------- chunk-batched fwd/bwd propagation + fused gold ------------
__global__ __launch_bounds__(256, 1) void crf_chunks(
    const float* __restrict__ pred, const float* __restrict__ trans,
    const int* __restrict__ ref, u64* __restrict__ pay, u32* __restrict__ fl,
    float* __restrict__ ybuf, float* __restrict__ zbuf,
    double* __restrict__ tlog, float* __restrict__ gold) {
  const int tid = threadIdx.x;
  const int wv = tid >> 6, l = tid & 63;
  const int lm = l & 15, lg = l >> 4;        // MFMA lane coords
  const int b = blockIdx.x;
  const int g = b & 31;                      // group (co-XCD parties: b%8==g%8)
  const int party = b >> 5;                  // 0..7
  const bool isFwd = (g < 16);
  const int cbase = (g & 15) * KCH;
  const int wb = 128 * party + 32 * wv;      // wave's first output row

  // ---- E fragments: fwd A[m=lm][k] = exp(trans[row][k]) (coalesced rows);
  // bwd needs exp(trans[k][col]) -> strided reads (16 lm-lanes x 4B = one
  // 64B line per (kt,lg,j): same transaction count as the coalesced path).
  f16x8 afrag0[32], afrag1[32];
  if (isFwd) {
    const float4* rp0 = (const float4*)&trans[(size_t)(wb + lm) * LLAB];
    const float4* rp1 = (const float4*)&trans[(size_t)(wb + 16 + lm) * LLAB];
#pragma unroll
    for (int kt = 0; kt < 32; ++kt) {
      float4 a = rp0[8 * kt + 2 * lg], c = rp0[8 * kt + 2 * lg + 1];
      f16x8 f;
      f[0] = (f16)__expf(a.x); f[1] = (f16)__expf(a.y);
      f[2] = (f16)__expf(a.z); f[3] = (f16)__expf(a.w);
      f[4] = (f16)__expf(c.x); f[5] = (f16)__expf(c.y);
      f[6] = (f16)__expf(c.z); f[7] = (f16)__expf(c.w);
      afrag0[kt] = f;
      a = rp1[8 * kt + 2 * lg]; c = rp1[8 * kt + 2 * lg + 1];
      f[0] = (f16)__expf(a.x); f[1] = (f16)__expf(a.y);
      f[2] = (f16)__expf(a.z); f[3] = (f16)__expf(a.w);
      f[4] = (f16)__expf(c.x); f[5] = (f16)__expf(c.y);
      f[6] = (f16)__expf(c.z); f[7] = (f16)__expf(c.w);
      afrag1[kt] = f;
    }
  } else {
    const int c0 = wb + lm, c1 = wb + 16 + lm;
#pragma unroll
    for (int kt = 0; kt < 32; ++kt) {
      f16x8 f0, f1;
#pragma unroll
      for (int j = 0; j < 8; ++j) {
        int k = 32 * kt + 8 * lg + j;
        f0[j] = (f16)__expf(trans[(size_t)k * LLAB + c0]);
        f1[j] = (f16)__expf(trans[(size_t)k * LLAB + c1]);
      }
      afrag0[kt] = f0; afrag1[kt] = f1;
    }
  }

  __shared__ __attribute__((aligned(16))) u32 qs[KCH * 512];   // 128 KB
  __shared__ float pmax[NPTY][KCH];                            // 2 KB

  u64* gp64 = pay + (size_t)g * 32768;   // [2 parity][8 party][2048 u64]
  u32* gfl  = fl + g * 512;              // [2 parity][8 party x 32-stride]

  // ---- init state: thread owns chunk gc=tid>>2, labels [256tp, 256tp+256)
  {
    const int gc = tid >> 2, tp = tid & 3;
    float m0, m1;   // party 2tp / 2tp+1 partial maxes
    if (isFwd) {
      uint4 ones = {0x3C003C00u, 0x3C003C00u, 0x3C003C00u, 0x3C003C00u};
#pragma unroll
      for (int i = 0; i < 32; ++i)
        *(uint4*)&qs[gc * 512 + swz(gc, 128 * tp + 4 * i)] = ones;
      m0 = m1 = 1.0f;
    } else {
      int trow = (cbase + gc) * BQ + BQ - 1;
      const float4* pp = (const float4*)&pred[(size_t)trow * LLAB + 256 * tp];
      m0 = m1 = 0.f;
#pragma unroll
      for (int i = 0; i < 32; ++i) {
        float4 e0 = pp[2 * i], e1 = pp[2 * i + 1];
        float a0 = __expf(e0.x), a1 = __expf(e0.y);
        float a2 = __expf(e0.z), a3 = __expf(e0.w);
        float a4 = __expf(e1.x), a5 = __expf(e1.y);
        float a6 = __expf(e1.z), a7 = __expf(e1.w);
        uint4 w4 = {pack2(a0, a1), pack2(a2, a3), pack2(a4, a5), pack2(a6, a7)};
        *(uint4*)&qs[gc * 512 + swz(gc, 128 * tp + 4 * i)] = w4;
        float mm = fmaxf(fmaxf(fmaxf(a0, a1), fmaxf(a2, a3)),
                         fmaxf(fmaxf(a4, a5), fmaxf(a6, a7)));
        if (i < 16) m0 = fmaxf(m0, mm); else m1 = fmaxf(m1, mm);
      }
    }
    pmax[2 * tp][gc] = m0; pmax[2 * tp + 1][gc] = m1;
  }
  __syncthreads();

  // emission prefetch for step 0 (fwd: t=tb; bwd: t=tb+BQ-2, input-side)
  float4 fe[8];
#pragma unroll
  for (int k = 0; k < 4; ++k) {
    int tb = (cbase + lm + 16 * k) * BQ;
    int tn = isFwd ? tb : (tb + BQ - 2);
    fe[2 * k]     = *(const float4*)&pred[(size_t)tn * LLAB + wb + 4 * lg];
    fe[2 * k + 1] = *(const float4*)&pred[(size_t)tn * LLAB + wb + 16 + 4 * lg];
  }

  const float C0 = 13359.727f;   // e^9.5 growth prior; residual tracked via u
  double up = 1.0;

  for (int s = 0; s < BQ; ++s) {
    const bool lastS = (s == BQ - 1);
    const int ps = s & 1;
    const u32 want = (u32)(s + 1);

    // per-tile u (self-combine over 8 party partials, fixed order -> bitwise
    // identical across all blocks; consistency is REQUIRED for correctness)
    float inv[4];
#pragma unroll
    for (int k = 0; k < 4; ++k) {
      int cn = lm + 16 * k;
      float u = pmax[0][cn];
#pragma unroll
      for (int p = 1; p < 8; ++p) u = fmaxf(u, pmax[p][cn]);
      inv[k] = 1.0f / (C0 * u);
    }
    if (tid < KCH) {
      float un = pmax[0][tid];
#pragma unroll
      for (int p = 1; p < 8; ++p) un = fmaxf(un, pmax[p][tid]);
      up *= (double)un;
    }

    // MFMA: 2 row-tiles x 4 chunk-tiles x 32 k-tiles; B from swizzled LDS
    f32x4 acc[4][2];
#pragma unroll
    for (int k = 0; k < 4; ++k) {
      acc[k][0] = {0.f, 0.f, 0.f, 0.f};
      acc[k][1] = {0.f, 0.f, 0.f, 0.f};
    }
#pragma unroll
    for (int kt = 0; kt < 32; ++kt) {
#pragma unroll
      for (int k = 0; k < 4; ++k) {
        int cn = lm + 16 * k;
        f16x8 bf = __builtin_bit_cast(f16x8,
            *(const uint4*)&qs[cn * 512 + swz(cn, 16 * kt + 4 * lg)]);
        acc[k][0] = __builtin_amdgcn_mfma_f32_16x16x32_f16(afrag0[kt], bf, acc[k][0], 0, 0, 0);
        acc[k][1] = __builtin_amdgcn_mfma_f32_16x16x32_f16(afrag1[kt], bf, acc[k][1], 0, 0, 0);
      }
    }

    // prefetch next step's emission rows (in flight across publish+spin)
    float4 nf[8];
#pragma unroll
    for (int k = 0; k < 8; ++k) nf[k] = fe[k];
    if (!lastS) {
#pragma unroll
      for (int k = 0; k < 4; ++k) {
        int tb = (cbase + lm + 16 * k) * BQ;
        int tn = isFwd ? (tb + s + 1) : (tb + BQ - 3 - s);
        if (tn < tb) tn = tb;      // bwd last-step value unused
        nf[2 * k]     = *(const float4*)&pred[(size_t)tn * LLAB + wb + 4 * lg];
        nf[2 * k + 1] = *(const float4*)&pred[(size_t)tn * LLAB + wb + 16 + 4 * lg];
      }
    }

    // fold emission (fwd: output-side; bwd: input-side for next matvec) + norm
    const bool fold = isFwd || !lastS;
    float o[8][4];
#pragma unroll
    for (int k = 0; k < 4; ++k) {
      float4 ea = fe[2 * k], eb = fe[2 * k + 1];
      float e0 = fold ? __expf(ea.x) : 1.f, e1 = fold ? __expf(ea.y) : 1.f;
      float e2 = fold ? __expf(ea.z) : 1.f, e3 = fold ? __expf(ea.w) : 1.f;
      float g0 = fold ? __expf(eb.x) : 1.f, g1 = fold ? __expf(eb.y) : 1.f;
      float g2 = fold ? __expf(eb.z) : 1.f, g3 = fold ? __expf(eb.w) : 1.f;
      o[2 * k][0] = acc[k][0][0] * e0 * inv[k];
      o[2 * k][1] = acc[k][0][1] * e1 * inv[k];
      o[2 * k][2] = acc[k][0][2] * e2 * inv[k];
      o[2 * k][3] = acc[k][0][3] * e3 * inv[k];
      o[2 * k + 1][0] = acc[k][1][0] * g0 * inv[k];
      o[2 * k + 1][1] = acc[k][1][1] * g1 * inv[k];
      o[2 * k + 1][2] = acc[k][1][2] * g2 * inv[k];
      o[2 * k + 1][3] = acc[k][1][3] * g3 * inv[k];
    }

    if (lastS) {  // write final chunk vectors (f32) to global
      float* dst = isFwd ? ybuf : zbuf;
#pragma unroll
      for (int k = 0; k < 4; ++k) {
        size_t base = (size_t)(cbase + lm + 16 * k) * LLAB + wb + 4 * lg;
#pragma unroll
        for (int r = 0; r < 4; ++r) {
          dst[base + r] = o[2 * k][r];
          dst[base + 16 + r] = o[2 * k + 1][r];
        }
      }
      break;
    }

    // publish: 8 relaxed sc1 atomic u64 stores (untagged payload -> MALL)
    {
      u64* op = gp64 + (size_t)ps * 16384 + party * 2048;
#pragma unroll
      for (int k = 0; k < 4; ++k) {
        int i64 = (lm + 16 * k) * 32 + 8 * wv + lg;
        pub64(op + i64,
              ((u64)pack2(o[2 * k][2], o[2 * k][3]) << 32) | pack2(o[2 * k][0], o[2 * k][1]));
        pub64(op + i64 + 4,
              ((u64)pack2(o[2 * k + 1][2], o[2 * k + 1][3]) << 32) | pack2(o[2 * k + 1][0], o[2 * k + 1][1]));
      }
    }
    __syncthreads();   // vmcnt(0): payload acked at MALL; qs/pmax reads done
    if (tid == 0)      // flag (relaxed; ordering established by the drain)
      __hip_atomic_store(gfl + ps * 256 + party * 32, want, __ATOMIC_RELAXED, AGT);

    // spin on 8 per-line party flags only
    {
      const u32* fp = gfl + ps * 256 + (l & 7) * 32;
      bool done = false;
      do {
        if (!done) done = (__hip_atomic_load(fp, __ATOMIC_RELAXED, AGT) >= want);
      } while (!__all(done));
    }

    // pull payload EXACTLY ONCE: 64 contiguous u64/thread (2 batches of 32),
    // thread covers party tid>>5, chunks 2*(tid&31)+{0,1}, all 128 labels
    {
      const u64* pb = gp64 + (size_t)ps * 16384 + (size_t)tid * 64;
      const int pp = tid >> 5;
      const int nb = 2 * (tid & 31);
#pragma unroll
      for (int half = 0; half < 2; ++half) {
        u64 gv[32];
#pragma unroll
        for (int m = 0; m < 32; ++m) gv[m] = ald64(pb + 32 * half + m);
        const int n = nb + half;
        float mm = 0.f;
#pragma unroll
        for (int q = 0; q < 16; ++q) {
          u64 w0 = gv[2 * q], w1 = gv[2 * q + 1];
          uint4 st = {(u32)w0, (u32)(w0 >> 32), (u32)w1, (u32)(w1 >> 32)};
          *(uint4*)&qs[n * 512 + swz(n, 64 * pp + 4 * q)] = st;
          mm = fmaxf(mm, max8(st));
        }
        pmax[pp][n] = mm;   // full party-slice max: no reduce needed
      }
    }
    __syncthreads();   // staging + pmax complete
#pragma unroll
    for (int k = 0; k < 8; ++k) fe[k] = nf[k];
  }

  // record bwd tau (log u products; stitch adds BQ*log(C0)); fwd tau cancels
  if (!isFwd && party == 0 && tid < KCH) tlog[cbase + tid] = log(up);

  // ---- fused gold path score: 64 timesteps per block (wave 0)
  if (tid < 64) {
    int t = b * 64 + tid;
    int r = ref[t];
    int prev = (t == 0) ? (LLAB - 2) : ref[t - 1];    // START = L-2
    float v = trans[(size_t)r * LLAB + prev] + pred[(size_t)t * LLAB + r];
    if (t == TT - 1) v += trans[(size_t)(LLAB - 1) * LLAB + r];  // STOP row
#pragma unroll
    for (int off = 32; off >= 1; off >>= 1) v += __shfl_xor(v, off);
    if (tid == 0) atomicAdd(gold, v);
  }
}

// ---------------- rank-1 stitch (4 seams/block) + fused final ----------------
__global__ __launch_bounds__(256) void crf_stitch(
    const float* __restrict__ ybuf, const float* __restrict__ zbuf,
    const double* __restrict__ tlog, const float* __restrict__ gold,
    double* __restrict__ dacc, u32* __restrict__ cnt, float* __restrict__ out) {
  const int tid = threadIdx.x;
  __shared__ double red[2][4];
  double local = 0.0;
  const double LC0 = log((double)13359.727f);
#pragma unroll
  for (int i = 0; i < 4; ++i) {
    const int cc = blockIdx.x * 4 + i;
    double na = 0.0, sa = 0.0;
    for (int j = tid; j < LLAB; j += 256) {
      double yv = (double)ybuf[(size_t)cc * LLAB + j];
      na += yv;
      double zz = (cc + 1 < NCH) ? (double)zbuf[(size_t)(cc + 1) * LLAB + j] : 1.0;
      sa += zz * yv;
    }
#pragma unroll
    for (int off = 32; off >= 1; off >>= 1) {
      na += __shfl_xor(na, off);
      sa += __shfl_xor(sa, off);
    }
    if ((tid & 63) == 0) { red[0][tid >> 6] = na; red[1][tid >> 6] = sa; }
    __syncthreads();
    if (tid == 0) {
      double n = red[0][0] + red[0][1] + red[0][2] + red[0][3];
      double sm = red[1][0] + red[1][1] + red[1][2] + red[1][3];
      local += log(sm) - log(n) + tlog[cc] + (double)BQ * LC0;
    }
    __syncthreads();
  }
  if (tid == 0) {
    atomicAdd(dacc, local);
    __threadfence();
    u32 old = atomicAdd(cnt, 1u);
    if (old == 255u) {     // last block: all dacc adds visible (fence chain)
      __threadfence();
      double s = __hip_atomic_load(dacc, __ATOMIC_RELAXED, AGT);
      out[0] = (float)(s + log((double)zbuf[LLAB - 2]) + NEGV - (double)gold[0]);
    }
  }
}

extern "C" void kernel_launch(void* const* d_in, const int* in_sizes, int n_in,
                              void* d_out, int out_size, void* d_ws, size_t ws_size,
                              hipStream_t stream) {
  const float* pred  = (const float*)d_in[0];   // (16384, 1024) f32
  const int*   ref   = (const int*)d_in[1];     // (16384,) i32
  const float* trans = (const float*)d_in[2];   // (1024, 1024) f32
  float* out = (float*)d_out;

  char* ws = (char*)d_ws;
  double* dacc = (double*)(ws + 0);                        // 8 B
  float* gold  = (float*)(ws + 8);                         // 4 B
  u32* cnt     = (u32*)(ws + 16);                          // 4 B
  u64* pay = (u64*)(ws + 1024);                            // 32*32768*8 = 8 MB
  size_t off = 1024 + (size_t)32 * 32768 * 8;
  u32* fl = (u32*)(ws + off);                              // 64 KB
  const size_t flbytes = (size_t)32 * 512 * 4;
  off += flbytes;
  float* ybuf = (float*)(ws + off); off += (size_t)NCH * LLAB * 4;   // 4 MB
  float* zbuf = (float*)(ws + off); off += (size_t)NCH * LLAB * 4;   // 4 MB
  double* tlog = (double*)(ws + off);                      // 8 KB

  hipMemsetAsync(ws, 0, 256, stream);            // dacc + gold + cnt
  hipMemsetAsync(fl, 0, flbytes, stream);        // reset flags every launch
  crf_chunks<<<256, 256, 0, stream>>>(pred, trans, ref, pay, fl, ybuf, zbuf,
                                      tlog, gold);
  crf_stitch<<<256, 256, 0, stream>>>(ybuf, zbuf, tlog, gold, dacc, cnt, out);
}

// Round 6
// 359.052 us; speedup vs baseline: 1.4435x; 1.4435x over previous
//
#include <hip/hip_runtime.h>

// CRF loss, T=16384, L=1024. v14: v12 core (BQ=32/KCH=32, 286us proven) with
// the sc1-pull wall attacked. Analysis: total pulled bytes are invariant to
// chunking (256 blocks x KCH*2KB x BQ steps = ~512MB since KCH*BQ=TT/16), and
// v12/v13 sustained only 1.2-1.8 TB/s -> TRANSACTION-limited (8B atomic loads).
// v14 transport:
//  - pull via inline-asm global_load_dwordx4 sc0 sc1 (16B, L1/L2-bypass,
//    MALL-coherent; relaxed-atomic-equivalent). 32x8B -> 14x16B per thread.
//    Explicit s_waitcnt vmcnt(0) + sched_barrier(0) before use (rule #18).
//  - own-party slice never pulled: producer writes its packed values straight
//    to LDS after the drain barrier (extra barrier makes it visible).
//  - publish unchanged: 4 relaxed sc1 atomic u64 stores -> __syncthreads
//    (vmcnt0 drain at MALL) -> per-party flag -> peers spin 8 flag lines.
// Aux: gold fused post-loop; transpose dropped (bwd A-init reads trans cols,
// 16 lm-lanes line-contiguous); stitch+final merged (completion counter);
// one merged memset. 3 dispatches total. Math identical to v12 (absmax 0).

#define TT    16384
#define LLAB  1024
#define NEGV  -10000.0
#define BQ    32            // steps per chunk
#define NCH   512           // chunks per direction (TT/BQ)
#define KCH   32            // chunks per group (2 MFMA N-tiles)
#define NPTY  8             // parties per group
#define AGT   __HIP_MEMORY_SCOPE_AGENT

typedef unsigned long long u64;
typedef unsigned int u32;
typedef unsigned short u16;
typedef _Float16 f16;
typedef _Float16 h2 __attribute__((ext_vector_type(2)));
typedef _Float16 f16x8 __attribute__((ext_vector_type(8)));
typedef float f32x4 __attribute__((ext_vector_type(4)));

__device__ __forceinline__ void pub64(u64* p, u64 v) {
  __hip_atomic_store(p, v, __ATOMIC_RELAXED, AGT);
}
// 16B load, L1+L2 bypass (system scope): reads current MALL content.
__device__ __forceinline__ uint4 ld16_sc(const u32* p) {
  uint4 r;
  asm volatile("global_load_dwordx4 %0, %1, off sc0 sc1"
               : "=v"(r) : "v"(p) : "memory");
  return r;
}
__device__ __forceinline__ u32 pack2(float a, float b) {
  h2 h = {(f16)a, (f16)b};
  return __builtin_bit_cast(u32, h);
}
__device__ __forceinline__ float f16lo(u32 b) {
  return (float)__builtin_bit_cast(f16, (u16)(b & 0xFFFFu));
}
__device__ __forceinline__ float f16hi(u32 b) {
  return (float)__builtin_bit_cast(f16, (u16)(b >> 16));
}
// XOR swizzle on u32-word index within a chunk's 512-word block (bits 2..4).
__device__ __forceinline__ int swz(int c, int w) { return w ^ ((c & 7) << 2); }

__device__ __forceinline__ float max8(uint4 v) {
  float m = fmaxf(fmaxf(f16lo(v.x), f16hi(v.x)), fmaxf(f16lo(v.y), f16hi(v.y)));
  m = fmaxf(m, fmaxf(f16lo(v.z), f16hi(v.z)));
  m = fmaxf(m, fmaxf(f16lo(v.w), f16hi(v.w)));
  return m;
}

// ---------------- chunk-batched fwd/bwd propagation + fused gold ------------
__global__ __launch_bounds__(256, 1) void crf_chunks(
    const float* __restrict__ pred, const float* __restrict__ trans,
    const int* __restrict__ ref, u32* __restrict__ pay, u32* __restrict__ fl,
    float* __restrict__ ybuf, float* __restrict__ zbuf,
    double* __restrict__ tlog, float* __restrict__ gold) {
  const int tid = threadIdx.x;
  const int wv = tid >> 6, l = tid & 63;
  const int lm = l & 15, lg = l >> 4;        // MFMA lane coords
  const int b = blockIdx.x;
  const int g = b & 31;                      // group (co-XCD parties: b%8==g%8)
  const int party = b >> 5;                  // 0..7
  const bool isFwd = (g < 16);
  const int cbase = (g & 15) * KCH;
  const int c1 = cbase + lm, c2 = cbase + lm + 16;
  const int tb1 = c1 * BQ, tb2 = c2 * BQ;
  const int wb = 128 * party + 32 * wv;      // wave's first output row

  // ---- E fragments: fwd A[m=lm][k] = exp(trans[wb+m][k]) (coalesced rows);
  // bwd A' = E^T rows = trans columns (16 lm-lanes x 4B line-contiguous).
  f16x8 afrag0[32], afrag1[32];
  if (isFwd) {
    const float4* rp0 = (const float4*)&trans[(size_t)(wb + lm) * LLAB];
    const float4* rp1 = (const float4*)&trans[(size_t)(wb + 16 + lm) * LLAB];
#pragma unroll
    for (int kt = 0; kt < 32; ++kt) {
      float4 a = rp0[8 * kt + 2 * lg], c = rp0[8 * kt + 2 * lg + 1];
      f16x8 f;
      f[0] = (f16)__expf(a.x); f[1] = (f16)__expf(a.y);
      f[2] = (f16)__expf(a.z); f[3] = (f16)__expf(a.w);
      f[4] = (f16)__expf(c.x); f[5] = (f16)__expf(c.y);
      f[6] = (f16)__expf(c.z); f[7] = (f16)__expf(c.w);
      afrag0[kt] = f;
      a = rp1[8 * kt + 2 * lg]; c = rp1[8 * kt + 2 * lg + 1];
      f[0] = (f16)__expf(a.x); f[1] = (f16)__expf(a.y);
      f[2] = (f16)__expf(a.z); f[3] = (f16)__expf(a.w);
      f[4] = (f16)__expf(c.x); f[5] = (f16)__expf(c.y);
      f[6] = (f16)__expf(c.z); f[7] = (f16)__expf(c.w);
      afrag1[kt] = f;
    }
  } else {
    const int c0 = wb + lm, cc1 = wb + 16 + lm;
#pragma unroll
    for (int kt = 0; kt < 32; ++kt) {
      f16x8 f0, f1;
#pragma unroll
      for (int j = 0; j < 8; ++j) {
        int k = 32 * kt + 8 * lg + j;
        f0[j] = (f16)__expf(trans[(size_t)k * LLAB + c0]);
        f1[j] = (f16)__expf(trans[(size_t)k * LLAB + cc1]);
      }
      afrag0[kt] = f0; afrag1[kt] = f1;
    }
  }

  __shared__ __attribute__((aligned(16))) u32 qs[KCH * 512];   // 64 KB
  __shared__ float smax[KCH];

  u32* gpay = pay + (size_t)g * 32768;   // [2 parity][8 party][2048 u32]
  u32* gfl  = fl + g * 512;              // [2 parity][8 party x 32-stride]

  // ---- init state: thread owns chunk gc=tid>>3, words 64*tp.. (labels x128)
  {
    const int gc = tid >> 3, tp = tid & 7;
    float mm;
    if (isFwd) {
      uint4 ones = {0x3C003C00u, 0x3C003C00u, 0x3C003C00u, 0x3C003C00u};
#pragma unroll
      for (int i = 0; i < 16; ++i)
        *(uint4*)&qs[gc * 512 + swz(gc, 64 * tp + 4 * i)] = ones;
      mm = 1.0f;
    } else {
      int trow = (cbase + gc) * BQ + BQ - 1;
      const float4* pp = (const float4*)&pred[(size_t)trow * LLAB + 128 * tp];
      mm = 0.f;
#pragma unroll
      for (int i = 0; i < 16; ++i) {
        float4 e0 = pp[2 * i], e1 = pp[2 * i + 1];
        float a0 = __expf(e0.x), a1 = __expf(e0.y);
        float a2 = __expf(e0.z), a3 = __expf(e0.w);
        float a4 = __expf(e1.x), a5 = __expf(e1.y);
        float a6 = __expf(e1.z), a7 = __expf(e1.w);
        uint4 w4 = {pack2(a0, a1), pack2(a2, a3), pack2(a4, a5), pack2(a6, a7)};
        *(uint4*)&qs[gc * 512 + swz(gc, 64 * tp + 4 * i)] = w4;
        mm = fmaxf(mm, fmaxf(fmaxf(a0, a1), fmaxf(a2, a3)));
        mm = fmaxf(mm, fmaxf(fmaxf(a4, a5), fmaxf(a6, a7)));
      }
#pragma unroll
      for (int off = 1; off <= 4; off <<= 1) mm = fmaxf(mm, __shfl_xor(mm, off));
    }
    if (tp == 0) smax[gc] = mm;
  }
  __syncthreads();

  // emission prefetch for step 0 (fwd: t=tb; bwd: t=tb+BQ-2, input-side)
  float4 fe1a, fe1b, fe2a, fe2b;
  {
    int t1 = isFwd ? tb1 : (tb1 + BQ - 2);
    int t2 = isFwd ? tb2 : (tb2 + BQ - 2);
    fe1a = *(const float4*)&pred[(size_t)t1 * LLAB + wb + 4 * lg];
    fe1b = *(const float4*)&pred[(size_t)t1 * LLAB + wb + 16 + 4 * lg];
    fe2a = *(const float4*)&pred[(size_t)t2 * LLAB + wb + 4 * lg];
    fe2b = *(const float4*)&pred[(size_t)t2 * LLAB + wb + 16 + 4 * lg];
  }

  const float C0 = 13359.727f;   // e^9.5 growth prior; residual tracked via u
  double up = 1.0;

  for (int s = 0; s < BQ; ++s) {
    const bool lastS = (s == BQ - 1);
    const int ps = s & 1;
    const u32 want = (u32)(s + 1);
    if (tid < KCH) up *= (double)smax[tid];
    const float i1 = 1.0f / (C0 * smax[lm]);
    const float i2 = 1.0f / (C0 * smax[lm + 16]);

    // MFMA: 2 row-tiles x 2 chunk-tiles x 32 k-tiles; B from swizzled LDS
    f32x4 a00 = {0.f, 0.f, 0.f, 0.f}, a01 = {0.f, 0.f, 0.f, 0.f};
    f32x4 a10 = {0.f, 0.f, 0.f, 0.f}, a11 = {0.f, 0.f, 0.f, 0.f};
#pragma unroll
    for (int kt = 0; kt < 32; ++kt) {
      f16x8 b1 = __builtin_bit_cast(f16x8,
          *(const uint4*)&qs[lm * 512 + swz(lm, 16 * kt + 4 * lg)]);
      f16x8 b2 = __builtin_bit_cast(f16x8,
          *(const uint4*)&qs[(lm + 16) * 512 + swz(lm + 16, 16 * kt + 4 * lg)]);
      a00 = __builtin_amdgcn_mfma_f32_16x16x32_f16(afrag0[kt], b1, a00, 0, 0, 0);
      a01 = __builtin_amdgcn_mfma_f32_16x16x32_f16(afrag1[kt], b1, a01, 0, 0, 0);
      a10 = __builtin_amdgcn_mfma_f32_16x16x32_f16(afrag0[kt], b2, a10, 0, 0, 0);
      a11 = __builtin_amdgcn_mfma_f32_16x16x32_f16(afrag1[kt], b2, a11, 0, 0, 0);
    }

    // prefetch next step's emission rows (in flight across publish+spin)
    float4 n1a = fe1a, n1b = fe1b, n2a = fe2a, n2b = fe2b;
    if (!lastS) {
      int sn = s + 1;
      int t1 = isFwd ? (tb1 + sn) : (tb1 + BQ - 2 - sn);
      int t2 = isFwd ? (tb2 + sn) : (tb2 + BQ - 2 - sn);
      if (t1 < tb1) t1 = tb1;     // bwd sn=BQ-1 value unused
      if (t2 < tb2) t2 = tb2;
      n1a = *(const float4*)&pred[(size_t)t1 * LLAB + wb + 4 * lg];
      n1b = *(const float4*)&pred[(size_t)t1 * LLAB + wb + 16 + 4 * lg];
      n2a = *(const float4*)&pred[(size_t)t2 * LLAB + wb + 4 * lg];
      n2b = *(const float4*)&pred[(size_t)t2 * LLAB + wb + 16 + 4 * lg];
    }

    // fold emission (fwd: output-side; bwd: input-side for next matvec) + norm
    const bool fold = isFwd || !lastS;
    float o00[4], o01[4], o10[4], o11[4];
    if (fold) {
      o00[0] = a00[0] * __expf(fe1a.x) * i1; o00[1] = a00[1] * __expf(fe1a.y) * i1;
      o00[2] = a00[2] * __expf(fe1a.z) * i1; o00[3] = a00[3] * __expf(fe1a.w) * i1;
      o01[0] = a01[0] * __expf(fe1b.x) * i1; o01[1] = a01[1] * __expf(fe1b.y) * i1;
      o01[2] = a01[2] * __expf(fe1b.z) * i1; o01[3] = a01[3] * __expf(fe1b.w) * i1;
      o10[0] = a10[0] * __expf(fe2a.x) * i2; o10[1] = a10[1] * __expf(fe2a.y) * i2;
      o10[2] = a10[2] * __expf(fe2a.z) * i2; o10[3] = a10[3] * __expf(fe2a.w) * i2;
      o11[0] = a11[0] * __expf(fe2b.x) * i2; o11[1] = a11[1] * __expf(fe2b.y) * i2;
      o11[2] = a11[2] * __expf(fe2b.z) * i2; o11[3] = a11[3] * __expf(fe2b.w) * i2;
    } else {
#pragma unroll
      for (int r = 0; r < 4; ++r) {
        o00[r] = a00[r] * i1; o01[r] = a01[r] * i1;
        o10[r] = a10[r] * i2; o11[r] = a11[r] * i2;
      }
    }

    if (lastS) {  // write final chunk vectors (f32) to global
      float* dst = isFwd ? ybuf : zbuf;
      size_t bb1 = (size_t)c1 * LLAB + wb + 4 * lg;
      size_t bb2 = (size_t)c2 * LLAB + wb + 4 * lg;
#pragma unroll
      for (int r = 0; r < 4; ++r) {
        dst[bb1 + r] = o00[r]; dst[bb1 + 16 + r] = o01[r];
        dst[bb2 + r] = o10[r]; dst[bb2 + 16 + r] = o11[r];
      }
      break;
    }

    // pack once; publish 4 relaxed sc1 atomic u64 (untagged payload -> MALL)
    const u32 q00 = pack2(o00[0], o00[1]), q01 = pack2(o00[2], o00[3]);
    const u32 q02 = pack2(o01[0], o01[1]), q03 = pack2(o01[2], o01[3]);
    const u32 q10 = pack2(o10[0], o10[1]), q11 = pack2(o10[2], o10[3]);
    const u32 q12 = pack2(o11[0], o11[1]), q13 = pack2(o11[2], o11[3]);
    {
      u64* op = (u64*)(gpay + (size_t)ps * 16384 + party * 2048);
      int i64 = lm * 32 + 8 * wv + lg;
      pub64(op + i64,       ((u64)q01 << 32) | q00);
      pub64(op + i64 + 4,   ((u64)q03 << 32) | q02);
      pub64(op + i64 + 512, ((u64)q11 << 32) | q10);
      pub64(op + i64 + 516, ((u64)q13 << 32) | q12);
    }
    __syncthreads();   // s_waitcnt vmcnt(0): payload acked at MALL; qs reads done
    if (tid == 0)      // flag (relaxed; ordering established by the drain)
      __hip_atomic_store(gfl + ps * 256 + party * 32, want, __ATOMIC_RELAXED, AGT);

    // self-slice straight to LDS (peers pull it; we never re-read from MALL)
    {
      int w = 16 * wv + 2 * lg;                 // u32 word within party slice
      uint2 s0 = {q00, q01}, s1 = {q02, q03}, s2 = {q10, q11}, s3 = {q12, q13};
      *(uint2*)&qs[lm * 512 + swz(lm, party * 64 + w)] = s0;
      *(uint2*)&qs[lm * 512 + swz(lm, party * 64 + w + 8)] = s1;
      *(uint2*)&qs[(lm + 16) * 512 + swz(lm + 16, party * 64 + w)] = s2;
      *(uint2*)&qs[(lm + 16) * 512 + swz(lm + 16, party * 64 + w + 8)] = s3;
    }
    __syncthreads();   // self-writes visible to stager threads

    // spin on 8 per-line party flags only
    {
      const u32* fp = gfl + ps * 256 + (l & 7) * 32;
      bool done = false;
      do {
        if (!done) done = (__hip_atomic_load(fp, __ATOMIC_RELAXED, AGT) >= want);
      } while (!__all(done));
    }

    // pull 7 peer parties x 2 dwordx4 (own slice already in LDS); stage + max
    {
      const u32* pb = gpay + (size_t)ps * 16384;
      const int c = tid >> 3, wbase = 8 * (tid & 7);
      uint4 gv[16];
#pragma unroll
      for (int p2 = 0; p2 < 8; ++p2) {
        if (p2 != party) {
          gv[2 * p2]     = ld16_sc(pb + p2 * 2048 + tid * 8);
          gv[2 * p2 + 1] = ld16_sc(pb + p2 * 2048 + tid * 8 + 4);
        }
      }
      asm volatile("s_waitcnt vmcnt(0)" ::: "memory");
      __builtin_amdgcn_sched_barrier(0);
      float mm = 0.f;
#pragma unroll
      for (int p2 = 0; p2 < 8; ++p2) {
        uint4 va, vb;
        if (p2 == party) {   // bitwise-identical values from the self-write
          va = *(const uint4*)&qs[c * 512 + swz(c, p2 * 64 + wbase)];
          vb = *(const uint4*)&qs[c * 512 + swz(c, p2 * 64 + wbase + 4)];
        } else {
          va = gv[2 * p2]; vb = gv[2 * p2 + 1];
          *(uint4*)&qs[c * 512 + swz(c, p2 * 64 + wbase)] = va;
          *(uint4*)&qs[c * 512 + swz(c, p2 * 64 + wbase + 4)] = vb;
        }
        mm = fmaxf(mm, fmaxf(max8(va), max8(vb)));
      }
#pragma unroll
      for (int off = 1; off <= 4; off <<= 1) mm = fmaxf(mm, __shfl_xor(mm, off));
      if ((tid & 7) == 0) smax[c] = mm;
    }
    __syncthreads();   // staging + smax complete
    fe1a = n1a; fe1b = n1b; fe2a = n2a; fe2b = n2b;
  }

  // record bwd tau (log u products; stitch adds BQ*log(C0)); fwd tau cancels
  if (!isFwd && party == 0 && tid < KCH) tlog[cbase + tid] = log(up);

  // ---- fused gold path score: 64 timesteps per block (wave 0)
  if (tid < 64) {
    int t = b * 64 + tid;
    int r = ref[t];
    int prev = (t == 0) ? (LLAB - 2) : ref[t - 1];    // START = L-2
    float v = trans[(size_t)r * LLAB + prev] + pred[(size_t)t * LLAB + r];
    if (t == TT - 1) v += trans[(size_t)(LLAB - 1) * LLAB + r];  // STOP row
#pragma unroll
    for (int off = 32; off >= 1; off >>= 1) v += __shfl_xor(v, off);
    if (tid == 0) atomicAdd(gold, v);
  }
}

// ---------------- rank-1 stitch (4 seams/block) + fused final ----------------
__global__ __launch_bounds__(256) void crf_stitch(
    const float* __restrict__ ybuf, const float* __restrict__ zbuf,
    const double* __restrict__ tlog, const float* __restrict__ gold,
    double* __restrict__ dacc, u32* __restrict__ cnt, float* __restrict__ out) {
  const int tid = threadIdx.x;
  __shared__ double red[2][4];
  double local = 0.0;
  const double LC0 = log((double)13359.727f);
#pragma unroll
  for (int i = 0; i < 4; ++i) {
    const int cc = blockIdx.x * 4 + i;
    double na = 0.0, sa = 0.0;
    for (int j = tid; j < LLAB; j += 256) {
      double yv = (double)ybuf[(size_t)cc * LLAB + j];
      na += yv;
      double zz = (cc + 1 < NCH) ? (double)zbuf[(size_t)(cc + 1) * LLAB + j] : 1.0;
      sa += zz * yv;
    }
#pragma unroll
    for (int off = 32; off >= 1; off >>= 1) {
      na += __shfl_xor(na, off);
      sa += __shfl_xor(sa, off);
    }
    if ((tid & 63) == 0) { red[0][tid >> 6] = na; red[1][tid >> 6] = sa; }
    __syncthreads();
    if (tid == 0) {
      double n = red[0][0] + red[0][1] + red[0][2] + red[0][3];
      double sm = red[1][0] + red[1][1] + red[1][2] + red[1][3];
      local += log(sm) - log(n) + tlog[cc] + (double)BQ * LC0;
    }
    __syncthreads();
  }
  if (tid == 0) {
    atomicAdd(dacc, local);
    __threadfence();
    u32 old = atomicAdd(cnt, 1u);
    if (old == 127u) {     // last of 128 blocks: all dacc adds visible
      __threadfence();
      double s = __hip_atomic_load(dacc, __ATOMIC_RELAXED, AGT);
      out[0] = (float)(s + log((double)zbuf[LLAB - 2]) + NEGV - (double)gold[0]);
    }
  }
}

extern "C" void kernel_launch(void* const* d_in, const int* in_sizes, int n_in,
                              void* d_out, int out_size, void* d_ws, size_t ws_size,
                              hipStream_t stream) {
  const float* pred  = (const float*)d_in[0];   // (16384, 1024) f32
  const int*   ref   = (const int*)d_in[1];     // (16384,) i32
  const float* trans = (const float*)d_in[2];   // (1024, 1024) f32
  float* out = (float*)d_out;

  char* ws = (char*)d_ws;
  double* dacc = (double*)(ws + 0);                        // 8 B
  float* gold  = (float*)(ws + 8);                         // 4 B
  u32* cnt     = (u32*)(ws + 16);                          // 4 B
  u32* fl      = (u32*)(ws + 256);                         // 32*512*4 = 64 KB
  u32* pay     = (u32*)(ws + 66560);                       // 32*32768*4 = 4 MB
  size_t off = 66560 + (size_t)32 * 32768 * 4;
  float* ybuf = (float*)(ws + off); off += (size_t)NCH * LLAB * 4;   // 2 MB
  float* zbuf = (float*)(ws + off); off += (size_t)NCH * LLAB * 4;   // 2 MB
  double* tlog = (double*)(ws + off);                      // 4 KB

  // one merged memset: header (dacc/gold/cnt) + all flags
  hipMemsetAsync(ws, 0, 66560, stream);
  crf_chunks<<<256, 256, 0, stream>>>(pred, trans, ref, pay, fl, ybuf, zbuf,
                                      tlog, gold);
  crf_stitch<<<128, 256, 0, stream>>>(ybuf, zbuf, tlog, gold, dacc, cnt, out);
}

// Round 7
// 343.875 us; speedup vs baseline: 1.5072x; 1.0441x over previous
//
#include <hip/hip_runtime.h>

// CRF loss, T=16384, L=1024. v15: v14 core (BQ=32/KCH=32, 277us) with the
// exchange made L2-broadcastable. v14 analysis: pulls are BW-limited --
// 448 MB of sc1 (L2-bypass) reads at ~1.6 TB/s ~= 280us, and 7/8 of those
// bytes are the SAME data re-read by the 7 peer parties. v15: WRITE-ONCE
// payload slots (one per group-step, 62 MB): no address reuse -> consumer
// plain (cached) reads are always-correct (first read misses L2, fills from
// MALL which holds the drained+flagged data; co-XCD peers then hit L2).
// Unique MALL traffic 448->64 MB; redundancy served by XCD L2 (~34 TB/s).
// Placement-independent correctness (worst case = all reads miss to MALL =
// v14 behavior). Flags: packed 8/64B-line (1 transaction/poll), polled by
// wave 0 only + s_sleep throttle (kills the 8-line x 4-wave poll storm).
// Runtime fallback if ws_size < ~70MB: v14's sc1 + 2-parity path (fastp=0).
// Aux: fused gold, merged stitch+final, bwd A-init from trans cols (v14).

#define TT    16384
#define LLAB  1024
#define NEGV  -10000.0
#define BQ    32            // steps per chunk
#define NCH   512           // chunks per direction (TT/BQ)
#define KCH   32            // chunks per group (2 MFMA N-tiles)
#define NPTY  8             // parties per group
#define AGT   __HIP_MEMORY_SCOPE_AGENT

typedef unsigned long long u64;
typedef unsigned int u32;
typedef unsigned short u16;
typedef _Float16 f16;
typedef _Float16 h2 __attribute__((ext_vector_type(2)));
typedef _Float16 f16x8 __attribute__((ext_vector_type(8)));
typedef float f32x4 __attribute__((ext_vector_type(4)));

__device__ __forceinline__ void pub64(u64* p, u64 v) {
  __hip_atomic_store(p, v, __ATOMIC_RELAXED, AGT);
}
// 16B load, L1+L2 bypass: reads current MALL content (fallback path).
__device__ __forceinline__ uint4 ld16_sc(const u32* p) {
  uint4 r;
  asm volatile("global_load_dwordx4 %0, %1, off sc0 sc1"
               : "=v"(r) : "v"(p) : "memory");
  return r;
}
__device__ __forceinline__ u32 pack2(float a, float b) {
  h2 h = {(f16)a, (f16)b};
  return __builtin_bit_cast(u32, h);
}
__device__ __forceinline__ float f16lo(u32 b) {
  return (float)__builtin_bit_cast(f16, (u16)(b & 0xFFFFu));
}
__device__ __forceinline__ float f16hi(u32 b) {
  return (float)__builtin_bit_cast(f16, (u16)(b >> 16));
}
// XOR swizzle on u32-word index within a chunk's 512-word block (bits 2..4).
__device__ __forceinline__ int swz(int c, int w) { return w ^ ((c & 7) << 2); }

__device__ __forceinline__ float max8(uint4 v) {
  float m = fmaxf(fmaxf(f16lo(v.x), f16hi(v.x)), fmaxf(f16lo(v.y), f16hi(v.y)));
  m = fmaxf(m, fmaxf(f16lo(v.z), f16hi(v.z)));
  m = fmaxf(m, fmaxf(f16lo(v.w), f16hi(v.w)));
  return m;
}

// ---------------- chunk-batched fwd/bwd propagation + fused gold ------------
__global__ __launch_bounds__(256, 1) void crf_chunks(
    const float* __restrict__ pred, const float* __restrict__ trans,
    const int* __restrict__ ref, u32* __restrict__ pay, u32* __restrict__ fl,
    float* __restrict__ ybuf, float* __restrict__ zbuf,
    double* __restrict__ tlog, float* __restrict__ gold, int fastp) {
  const int tid = threadIdx.x;
  const int wv = tid >> 6, l = tid & 63;
  const int lm = l & 15, lg = l >> 4;        // MFMA lane coords
  const int b = blockIdx.x;
  const int g = b & 31;                      // group (co-XCD parties: b%8==g%8)
  const int party = b >> 5;                  // 0..7
  const bool isFwd = (g < 16);
  const int cbase = (g & 15) * KCH;
  const int c1 = cbase + lm, c2 = cbase + lm + 16;
  const int tb1 = c1 * BQ, tb2 = c2 * BQ;
  const int wb = 128 * party + 32 * wv;      // wave's first output row

  // ---- E fragments: fwd A[m=lm][k] = exp(trans[wb+m][k]) (coalesced rows);
  // bwd A' = E^T rows = trans columns (16 lm-lanes x 4B line-contiguous).
  f16x8 afrag0[32], afrag1[32];
  if (isFwd) {
    const float4* rp0 = (const float4*)&trans[(size_t)(wb + lm) * LLAB];
    const float4* rp1 = (const float4*)&trans[(size_t)(wb + 16 + lm) * LLAB];
#pragma unroll
    for (int kt = 0; kt < 32; ++kt) {
      float4 a = rp0[8 * kt + 2 * lg], c = rp0[8 * kt + 2 * lg + 1];
      f16x8 f;
      f[0] = (f16)__expf(a.x); f[1] = (f16)__expf(a.y);
      f[2] = (f16)__expf(a.z); f[3] = (f16)__expf(a.w);
      f[4] = (f16)__expf(c.x); f[5] = (f16)__expf(c.y);
      f[6] = (f16)__expf(c.z); f[7] = (f16)__expf(c.w);
      afrag0[kt] = f;
      a = rp1[8 * kt + 2 * lg]; c = rp1[8 * kt + 2 * lg + 1];
      f[0] = (f16)__expf(a.x); f[1] = (f16)__expf(a.y);
      f[2] = (f16)__expf(a.z); f[3] = (f16)__expf(a.w);
      f[4] = (f16)__expf(c.x); f[5] = (f16)__expf(c.y);
      f[6] = (f16)__expf(c.z); f[7] = (f16)__expf(c.w);
      afrag1[kt] = f;
    }
  } else {
    const int c0 = wb + lm, cc1 = wb + 16 + lm;
#pragma unroll
    for (int kt = 0; kt < 32; ++kt) {
      f16x8 f0, f1;
#pragma unroll
      for (int j = 0; j < 8; ++j) {
        int k = 32 * kt + 8 * lg + j;
        f0[j] = (f16)__expf(trans[(size_t)k * LLAB + c0]);
        f1[j] = (f16)__expf(trans[(size_t)k * LLAB + cc1]);
      }
      afrag0[kt] = f0; afrag1[kt] = f1;
    }
  }

  __shared__ __attribute__((aligned(16))) u32 qs[KCH * 512];   // 64 KB
  __shared__ float smax[KCH];

  u32* gfl = fl + g * 16;   // 8 party-flags packed in one 64B line per group

  // ---- init state: thread owns chunk gc=tid>>3, words 64*tp.. (labels x128)
  {
    const int gc = tid >> 3, tp = tid & 7;
    float mm;
    if (isFwd) {
      uint4 ones = {0x3C003C00u, 0x3C003C00u, 0x3C003C00u, 0x3C003C00u};
#pragma unroll
      for (int i = 0; i < 16; ++i)
        *(uint4*)&qs[gc * 512 + swz(gc, 64 * tp + 4 * i)] = ones;
      mm = 1.0f;
    } else {
      int trow = (cbase + gc) * BQ + BQ - 1;
      const float4* pp = (const float4*)&pred[(size_t)trow * LLAB + 128 * tp];
      mm = 0.f;
#pragma unroll
      for (int i = 0; i < 16; ++i) {
        float4 e0 = pp[2 * i], e1 = pp[2 * i + 1];
        float a0 = __expf(e0.x), a1 = __expf(e0.y);
        float a2 = __expf(e0.z), a3 = __expf(e0.w);
        float a4 = __expf(e1.x), a5 = __expf(e1.y);
        float a6 = __expf(e1.z), a7 = __expf(e1.w);
        uint4 w4 = {pack2(a0, a1), pack2(a2, a3), pack2(a4, a5), pack2(a6, a7)};
        *(uint4*)&qs[gc * 512 + swz(gc, 64 * tp + 4 * i)] = w4;
        mm = fmaxf(mm, fmaxf(fmaxf(a0, a1), fmaxf(a2, a3)));
        mm = fmaxf(mm, fmaxf(fmaxf(a4, a5), fmaxf(a6, a7)));
      }
#pragma unroll
      for (int off = 1; off <= 4; off <<= 1) mm = fmaxf(mm, __shfl_xor(mm, off));
    }
    if (tp == 0) smax[gc] = mm;
  }
  __syncthreads();

  // emission prefetch for step 0 (fwd: t=tb; bwd: t=tb+BQ-2, input-side)
  float4 fe1a, fe1b, fe2a, fe2b;
  {
    int t1 = isFwd ? tb1 : (tb1 + BQ - 2);
    int t2 = isFwd ? tb2 : (tb2 + BQ - 2);
    fe1a = *(const float4*)&pred[(size_t)t1 * LLAB + wb + 4 * lg];
    fe1b = *(const float4*)&pred[(size_t)t1 * LLAB + wb + 16 + 4 * lg];
    fe2a = *(const float4*)&pred[(size_t)t2 * LLAB + wb + 4 * lg];
    fe2b = *(const float4*)&pred[(size_t)t2 * LLAB + wb + 16 + 4 * lg];
  }

  const float C0 = 13359.727f;   // e^9.5 growth prior; residual tracked via u
  double up = 1.0;

  for (int s = 0; s < BQ; ++s) {
    const bool lastS = (s == BQ - 1);
    const u32 want = (u32)(s + 1);
    // write-once slot (fastp) or 2-parity slot (fallback), 16384 u32 each
    const size_t stepBase = fastp
        ? (size_t)16384 * ((size_t)g * (BQ - 1) + (size_t)s)
        : (size_t)g * 32768 + (size_t)(s & 1) * 16384;
    u32* sp = pay + stepBase;
    if (tid < KCH) up *= (double)smax[tid];
    const float i1 = 1.0f / (C0 * smax[lm]);
    const float i2 = 1.0f / (C0 * smax[lm + 16]);

    // MFMA: 2 row-tiles x 2 chunk-tiles x 32 k-tiles; B from swizzled LDS
    f32x4 a00 = {0.f, 0.f, 0.f, 0.f}, a01 = {0.f, 0.f, 0.f, 0.f};
    f32x4 a10 = {0.f, 0.f, 0.f, 0.f}, a11 = {0.f, 0.f, 0.f, 0.f};
#pragma unroll
    for (int kt = 0; kt < 32; ++kt) {
      f16x8 b1 = __builtin_bit_cast(f16x8,
          *(const uint4*)&qs[lm * 512 + swz(lm, 16 * kt + 4 * lg)]);
      f16x8 b2 = __builtin_bit_cast(f16x8,
          *(const uint4*)&qs[(lm + 16) * 512 + swz(lm + 16, 16 * kt + 4 * lg)]);
      a00 = __builtin_amdgcn_mfma_f32_16x16x32_f16(afrag0[kt], b1, a00, 0, 0, 0);
      a01 = __builtin_amdgcn_mfma_f32_16x16x32_f16(afrag1[kt], b1, a01, 0, 0, 0);
      a10 = __builtin_amdgcn_mfma_f32_16x16x32_f16(afrag0[kt], b2, a10, 0, 0, 0);
      a11 = __builtin_amdgcn_mfma_f32_16x16x32_f16(afrag1[kt], b2, a11, 0, 0, 0);
    }

    // prefetch next step's emission rows (in flight across publish+spin)
    float4 n1a = fe1a, n1b = fe1b, n2a = fe2a, n2b = fe2b;
    if (!lastS) {
      int sn = s + 1;
      int t1 = isFwd ? (tb1 + sn) : (tb1 + BQ - 2 - sn);
      int t2 = isFwd ? (tb2 + sn) : (tb2 + BQ - 2 - sn);
      if (t1 < tb1) t1 = tb1;     // bwd sn=BQ-1 value unused
      if (t2 < tb2) t2 = tb2;
      n1a = *(const float4*)&pred[(size_t)t1 * LLAB + wb + 4 * lg];
      n1b = *(const float4*)&pred[(size_t)t1 * LLAB + wb + 16 + 4 * lg];
      n2a = *(const float4*)&pred[(size_t)t2 * LLAB + wb + 4 * lg];
      n2b = *(const float4*)&pred[(size_t)t2 * LLAB + wb + 16 + 4 * lg];
    }

    // fold emission (fwd: output-side; bwd: input-side for next matvec) + norm
    const bool fold = isFwd || !lastS;
    float o00[4], o01[4], o10[4], o11[4];
    if (fold) {
      o00[0] = a00[0] * __expf(fe1a.x) * i1; o00[1] = a00[1] * __expf(fe1a.y) * i1;
      o00[2] = a00[2] * __expf(fe1a.z) * i1; o00[3] = a00[3] * __expf(fe1a.w) * i1;
      o01[0] = a01[0] * __expf(fe1b.x) * i1; o01[1] = a01[1] * __expf(fe1b.y) * i1;
      o01[2] = a01[2] * __expf(fe1b.z) * i1; o01[3] = a01[3] * __expf(fe1b.w) * i1;
      o10[0] = a10[0] * __expf(fe2a.x) * i2; o10[1] = a10[1] * __expf(fe2a.y) * i2;
      o10[2] = a10[2] * __expf(fe2a.z) * i2; o10[3] = a10[3] * __expf(fe2a.w) * i2;
      o11[0] = a11[0] * __expf(fe2b.x) * i2; o11[1] = a11[1] * __expf(fe2b.y) * i2;
      o11[2] = a11[2] * __expf(fe2b.z) * i2; o11[3] = a11[3] * __expf(fe2b.w) * i2;
    } else {
#pragma unroll
      for (int r = 0; r < 4; ++r) {
        o00[r] = a00[r] * i1; o01[r] = a01[r] * i1;
        o10[r] = a10[r] * i2; o11[r] = a11[r] * i2;
      }
    }

    if (lastS) {  // write final chunk vectors (f32) to global
      float* dst = isFwd ? ybuf : zbuf;
      size_t bb1 = (size_t)c1 * LLAB + wb + 4 * lg;
      size_t bb2 = (size_t)c2 * LLAB + wb + 4 * lg;
#pragma unroll
      for (int r = 0; r < 4; ++r) {
        dst[bb1 + r] = o00[r]; dst[bb1 + 16 + r] = o01[r];
        dst[bb2 + r] = o10[r]; dst[bb2 + 16 + r] = o11[r];
      }
      break;
    }

    // pack once; publish 4 relaxed sc1 atomic u64 (write-through to MALL)
    const u32 q00 = pack2(o00[0], o00[1]), q01 = pack2(o00[2], o00[3]);
    const u32 q02 = pack2(o01[0], o01[1]), q03 = pack2(o01[2], o01[3]);
    const u32 q10 = pack2(o10[0], o10[1]), q11 = pack2(o10[2], o10[3]);
    const u32 q12 = pack2(o11[0], o11[1]), q13 = pack2(o11[2], o11[3]);
    {
      u64* op = (u64*)sp + (size_t)party * 1024;
      int i64 = lm * 32 + 8 * wv + lg;
      pub64(op + i64,       ((u64)q01 << 32) | q00);
      pub64(op + i64 + 4,   ((u64)q03 << 32) | q02);
      pub64(op + i64 + 512, ((u64)q11 << 32) | q10);
      pub64(op + i64 + 516, ((u64)q13 << 32) | q12);
    }
    __syncthreads();   // s_waitcnt vmcnt(0): payload acked at MALL; qs reads done
    if (tid == 0)      // monotone per-party flag (8 packed in one line)
      __hip_atomic_store(gfl + party, want, __ATOMIC_RELAXED, AGT);

    // self-slice straight to LDS (peers pull it; we never re-read it)
    {
      int w = 16 * wv + 2 * lg;                 // u32 word within party slice
      uint2 s0 = {q00, q01}, s1 = {q02, q03}, s2 = {q10, q11}, s3 = {q12, q13};
      *(uint2*)&qs[lm * 512 + swz(lm, party * 64 + w)] = s0;
      *(uint2*)&qs[lm * 512 + swz(lm, party * 64 + w + 8)] = s1;
      *(uint2*)&qs[(lm + 16) * 512 + swz(lm + 16, party * 64 + w)] = s2;
      *(uint2*)&qs[(lm + 16) * 512 + swz(lm + 16, party * 64 + w + 8)] = s3;
    }

    // wave 0 polls the group's packed flag line (1 transaction/poll, throttled)
    if (wv == 0) {
      const u32* fp = gfl + (l & 7);
      bool done = false;
      while (true) {
        if (!done) done = (__hip_atomic_load(fp, __ATOMIC_RELAXED, AGT) >= want);
        if (__all(done)) break;
        __builtin_amdgcn_s_sleep(2);
      }
    }
    __syncthreads();   // flag seen + self-writes visible to all waves

    // pull 7 peer slices: plain cached dwordx4 (fastp: write-once addresses ->
    // first read L2-misses to MALL, co-XCD peers hit L2) or sc1 (fallback)
    {
      const u32* pb = sp;
      const int c = tid >> 3, wbase = 8 * (tid & 7);
      uint4 gv[16];
      if (fastp) {
#pragma unroll
        for (int p2 = 0; p2 < 8; ++p2) {
          if (p2 != party) {
            gv[2 * p2]     = *(const uint4*)(pb + p2 * 2048 + tid * 8);
            gv[2 * p2 + 1] = *(const uint4*)(pb + p2 * 2048 + tid * 8 + 4);
          }
        }
      } else {
#pragma unroll
        for (int p2 = 0; p2 < 8; ++p2) {
          if (p2 != party) {
            gv[2 * p2]     = ld16_sc(pb + p2 * 2048 + tid * 8);
            gv[2 * p2 + 1] = ld16_sc(pb + p2 * 2048 + tid * 8 + 4);
          }
        }
        asm volatile("s_waitcnt vmcnt(0)" ::: "memory");
        __builtin_amdgcn_sched_barrier(0);
      }
      float mm = 0.f;
#pragma unroll
      for (int p2 = 0; p2 < 8; ++p2) {
        uint4 va, vb;
        if (p2 == party) {   // bitwise-identical values from the self-write
          va = *(const uint4*)&qs[c * 512 + swz(c, p2 * 64 + wbase)];
          vb = *(const uint4*)&qs[c * 512 + swz(c, p2 * 64 + wbase + 4)];
        } else {
          va = gv[2 * p2]; vb = gv[2 * p2 + 1];
          *(uint4*)&qs[c * 512 + swz(c, p2 * 64 + wbase)] = va;
          *(uint4*)&qs[c * 512 + swz(c, p2 * 64 + wbase + 4)] = vb;
        }
        mm = fmaxf(mm, fmaxf(max8(va), max8(vb)));
      }
#pragma unroll
      for (int off = 1; off <= 4; off <<= 1) mm = fmaxf(mm, __shfl_xor(mm, off));
      if ((tid & 7) == 0) smax[c] = mm;
    }
    __syncthreads();   // staging + smax complete
    fe1a = n1a; fe1b = n1b; fe2a = n2a; fe2b = n2b;
  }

  // record bwd tau (log u products; stitch adds BQ*log(C0)); fwd tau cancels
  if (!isFwd && party == 0 && tid < KCH) tlog[cbase + tid] = log(up);

  // ---- fused gold path score: 64 timesteps per block (wave 0)
  if (tid < 64) {
    int t = b * 64 + tid;
    int r = ref[t];
    int prev = (t == 0) ? (LLAB - 2) : ref[t - 1];    // START = L-2
    float v = trans[(size_t)r * LLAB + prev] + pred[(size_t)t * LLAB + r];
    if (t == TT - 1) v += trans[(size_t)(LLAB - 1) * LLAB + r];  // STOP row
#pragma unroll
    for (int off = 32; off >= 1; off >>= 1) v += __shfl_xor(v, off);
    if (tid == 0) atomicAdd(gold, v);
  }
}

// ---------------- rank-1 stitch (4 seams/block) + fused final ----------------
__global__ __launch_bounds__(256) void crf_stitch(
    const float* __restrict__ ybuf, const float* __restrict__ zbuf,
    const double* __restrict__ tlog, const float* __restrict__ gold,
    double* __restrict__ dacc, u32* __restrict__ cnt, float* __restrict__ out) {
  const int tid = threadIdx.x;
  __shared__ double red[2][4];
  double local = 0.0;
  const double LC0 = log((double)13359.727f);
#pragma unroll
  for (int i = 0; i < 4; ++i) {
    const int cc = blockIdx.x * 4 + i;
    double na = 0.0, sa = 0.0;
    for (int j = tid; j < LLAB; j += 256) {
      double yv = (double)ybuf[(size_t)cc * LLAB + j];
      na += yv;
      double zz = (cc + 1 < NCH) ? (double)zbuf[(size_t)(cc + 1) * LLAB + j] : 1.0;
      sa += zz * yv;
    }
#pragma unroll
    for (int off = 32; off >= 1; off >>= 1) {
      na += __shfl_xor(na, off);
      sa += __shfl_xor(sa, off);
    }
    if ((tid & 63) == 0) { red[0][tid >> 6] = na; red[1][tid >> 6] = sa; }
    __syncthreads();
    if (tid == 0) {
      double n = red[0][0] + red[0][1] + red[0][2] + red[0][3];
      double sm = red[1][0] + red[1][1] + red[1][2] + red[1][3];
      local += log(sm) - log(n) + tlog[cc] + (double)BQ * LC0;
    }
    __syncthreads();
  }
  if (tid == 0) {
    atomicAdd(dacc, local);
    __threadfence();
    u32 old = atomicAdd(cnt, 1u);
    if (old == 127u) {     // last of 128 blocks: all dacc adds visible
      __threadfence();
      double s = __hip_atomic_load(dacc, __ATOMIC_RELAXED, AGT);
      out[0] = (float)(s + log((double)zbuf[LLAB - 2]) + NEGV - (double)gold[0]);
    }
  }
}

extern "C" void kernel_launch(void* const* d_in, const int* in_sizes, int n_in,
                              void* d_out, int out_size, void* d_ws, size_t ws_size,
                              hipStream_t stream) {
  const float* pred  = (const float*)d_in[0];   // (16384, 1024) f32
  const int*   ref   = (const int*)d_in[1];     // (16384,) i32
  const float* trans = (const float*)d_in[2];   // (1024, 1024) f32
  float* out = (float*)d_out;

  char* ws = (char*)d_ws;
  double* dacc = (double*)(ws + 0);                        // 8 B
  float* gold  = (float*)(ws + 8);                         // 4 B
  u32* cnt     = (u32*)(ws + 16);                          // 4 B
  u32* fl      = (u32*)(ws + 256);                         // 32 groups x 64 B

  const size_t payFast  = (size_t)32 * (BQ - 1) * 16384 * 4;  // ~62 MB
  const size_t paySmall = (size_t)32 * 2 * 16384 * 4;         // 4 MB
  const size_t tail = (size_t)NCH * LLAB * 4 * 2 + 8192;      // y + z + tlog
  const int fastp = (ws_size >= 4096 + payFast + tail) ? 1 : 0;
  const size_t paySz = fastp ? payFast : paySmall;

  u32* pay = (u32*)(ws + 4096);
  size_t off = 4096 + paySz;
  float* ybuf = (float*)(ws + off); off += (size_t)NCH * LLAB * 4;   // 2 MB
  float* zbuf = (float*)(ws + off); off += (size_t)NCH * LLAB * 4;   // 2 MB
  double* tlog = (double*)(ws + off);                      // 4 KB

  // one memset: header (dacc/gold/cnt) + packed flags
  hipMemsetAsync(ws, 0, 4096, stream);
  crf_chunks<<<256, 256, 0, stream>>>(pred, trans, ref, pay, fl, ybuf, zbuf,
                                      tlog, gold, fastp);
  crf_stitch<<<128, 256, 0, stream>>>(ybuf, zbuf, tlog, gold, dacc, cnt, out);
}